// Round 4
// baseline (274.763 us; speedup 1.0000x reference)
//
#include <hip/hip_runtime.h>
#include <cstdint>
#include <math.h>

// ---------------------------------------------------------------------------
// Bit-exact replication of jax.random with threefry_partitionable=True:
//   split(key)      -> key[i] = threefry(key; hi=0, lo=i)  (foldlike)
//   random_bits 32b -> o0 ^ o1 of threefry(key; hi=0, lo=flat_idx)
//   kp, ku = split(key(42)); key data = (0,42)
//   n_raw = poisson_knuth(kp, 2.0)[row]           (data-INDEPENDENT)
//   n = where(nv>1, min(n_raw, nv-1), 0)
//   scores = where(valid, uniform(ku,(B,128)), -1); drop top-n (stable ties)
//
// Structure:
//  * Pre-kernel: one lane per row runs the Knuth chain with HOST-precomputed
//    subkeys (rng-split chain is row-independent); writes n_raw (u8) to d_ws.
//  * Main kernel: ONE WAVE PER ROW (2 cols/lane). n_raw is wave-uniform, so
//    rows with n==0 (P = e^-2*(1+2) ~ 40.6%) skip all 128 score hashes and
//    the extraction loop with zero divergence -> pure copy path.
// ---------------------------------------------------------------------------

#define DH __host__ __device__ __forceinline__

DH uint32_t rotl32(uint32_t v, uint32_t r) { return (v << r) | (v >> (32u - r)); }

// Threefry-2x32, 20 rounds (matches jax threefry2x32)
DH void tf2x32(uint32_t k0, uint32_t k1, uint32_t x0, uint32_t x1,
               uint32_t& o0, uint32_t& o1) {
  const uint32_t k2 = k0 ^ k1 ^ 0x1BD11BDAu;
  x0 += k0; x1 += k1;
  x0 += x1; x1 = rotl32(x1, 13); x1 ^= x0;
  x0 += x1; x1 = rotl32(x1, 15); x1 ^= x0;
  x0 += x1; x1 = rotl32(x1, 26); x1 ^= x0;
  x0 += x1; x1 = rotl32(x1,  6); x1 ^= x0;
  x0 += k1; x1 += k2 + 1u;
  x0 += x1; x1 = rotl32(x1, 17); x1 ^= x0;
  x0 += x1; x1 = rotl32(x1, 29); x1 ^= x0;
  x0 += x1; x1 = rotl32(x1, 16); x1 ^= x0;
  x0 += x1; x1 = rotl32(x1, 24); x1 ^= x0;
  x0 += k2; x1 += k0 + 2u;
  x0 += x1; x1 = rotl32(x1, 13); x1 ^= x0;
  x0 += x1; x1 = rotl32(x1, 15); x1 ^= x0;
  x0 += x1; x1 = rotl32(x1, 26); x1 ^= x0;
  x0 += x1; x1 = rotl32(x1,  6); x1 ^= x0;
  x0 += k0; x1 += k1 + 3u;
  x0 += x1; x1 = rotl32(x1, 17); x1 ^= x0;
  x0 += x1; x1 = rotl32(x1, 29); x1 ^= x0;
  x0 += x1; x1 = rotl32(x1, 16); x1 ^= x0;
  x0 += x1; x1 = rotl32(x1, 24); x1 ^= x0;
  x0 += k1; x1 += k2 + 4u;
  x0 += x1; x1 = rotl32(x1, 13); x1 ^= x0;
  x0 += x1; x1 = rotl32(x1, 15); x1 ^= x0;
  x0 += x1; x1 = rotl32(x1, 26); x1 ^= x0;
  x0 += x1; x1 = rotl32(x1,  6); x1 ^= x0;
  x0 += k2; x1 += k0 + 5u;
  o0 = x0; o1 = x1;
}

__device__ __forceinline__ float u01(uint32_t bits) {
  // jax.random.uniform: bitcast((bits>>9)|0x3f800000) - 1.0  (exact)
  return __uint_as_float((bits >> 9) | 0x3f800000u) - 1.0f;
}

struct PoisKeys { uint32_t s0[32]; uint32_t s1[32]; };

// One lane per row: Knuth Poisson(2) with precomputed per-iteration subkeys.
// P(Poisson(2) >= 32) ~ 1e-25 -> 32 iterations always suffice.
__global__ __launch_bounds__(256) void pois_kernel(
    uint8_t* __restrict__ nout, int B, PoisKeys pk) {
  const int row = (int)(blockIdx.x * 256u + threadIdx.x);
  if (row >= B) return;
  float lp = 0.0f;
  int k = 0;
  for (int it = 0; it < 32; ++it) {
    if (lp <= -2.0f) break;
    uint32_t b0, b1;
    tf2x32(pk.s0[it], pk.s1[it], 0u, (uint32_t)row, b0, b1);
    ++k;
    // correctly-rounded f32 log via f64; accumulate in f32 like the reference
    lp += (float)log((double)u01(b0 ^ b1));
  }
  nout[row] = (uint8_t)(k - 1);
}

// One WAVE per row; lane owns cols (2*lane, 2*lane+1). No LDS, no barriers.
__global__ __launch_bounds__(256) void rfm_kernel(
    const float* __restrict__ x, const float* __restrict__ mask,
    const uint8_t* __restrict__ nraw, float* __restrict__ out, int B,
    uint32_t ku0, uint32_t ku1) {
  const int row = (int)(blockIdx.x * 4u + (threadIdx.x >> 6));
  if (row >= B) return;
  const int lane = (int)(threadIdx.x & 63u);
  const int c0 = lane * 2, c1 = c0 + 1;
  const size_t base = (size_t)row * 128u + (size_t)c0;
  const size_t NF = (size_t)B * 128u;

  const float2 m2 = *(const float2*)(mask + base);
  const float2 x2 = *(const float2*)(x + base);
  int n = (int)nraw[row];           // wave-uniform

  float ox0 = x2.x, ox1 = x2.y, om0 = m2.x, om1 = m2.y;

  if (n > 0) {                      // wave-uniform branch: 40.6% skip entirely
    const bool v0 = m2.x > 0.5f, v1 = m2.y > 0.5f;
    const unsigned long long bal0 = __ballot(v0);
    const unsigned long long bal1 = __ballot(v1);
    const int nv = __popcll(bal0) + __popcll(bal1);
    n = (nv > 1) ? min(n, nv - 1) : 0;

    if (n > 0) {
      // scores: uniform(ku,(B,128)); bits = o0^o1 of tf(ku; 0, flat_idx)
      const uint32_t idx = (uint32_t)row * 128u + (uint32_t)c0;
      uint32_t a0, a1, b0, b1;
      tf2x32(ku0, ku1, 0u, idx,      a0, a1);
      tf2x32(ku0, ku1, 0u, idx + 1u, b0, b1);
      float s0 = v0 ? u01(a0 ^ a1) : -1.0f;
      float s1 = v1 ? u01(b0 ^ b1) : -1.0f;

      // drop the n highest-scoring positions (ties -> lower column index,
      // matching stable argsort; top-n always valid since n <= nv-1)
      for (int t = 0; t < n; ++t) {
        float bs; int bc;
        if (s1 > s0) { bs = s1; bc = c1; } else { bs = s0; bc = c0; }
#pragma unroll
        for (int off = 32; off; off >>= 1) {   // 64-lane butterfly argmax
          const float os = __shfl_xor(bs, off);
          const int   oc = __shfl_xor(bc, off);
          if (os > bs || (os == bs && oc < bc)) { bs = os; bc = oc; }
        }
        if (bc == c0)      { s0 = -2.0f; ox0 = 0.0f; om0 = 0.0f; }
        else if (bc == c1) { s1 = -2.0f; ox1 = 0.0f; om1 = 0.0f; }
      }
    }
  }

  float2 o;
  o.x = ox0; o.y = ox1; *(float2*)(out + base)      = o;
  o.x = om0; o.y = om1; *(float2*)(out + NF + base) = o;
}

extern "C" void kernel_launch(void* const* d_in, const int* in_sizes, int n_in,
                              void* d_out, int out_size, void* d_ws, size_t ws_size,
                              hipStream_t stream) {
  const float* x    = (const float*)d_in[0];
  const float* mask = (const float*)d_in[1];
  float* out = (float*)d_out;
  uint8_t* nws = (uint8_t*)d_ws;    // B bytes of scratch for n_raw

  const int B = in_sizes[0] / 128;  // 500000

  // kp, ku = jax.random.split(jax.random.key(42)); key data = (0,42)
  // partitionable/foldlike: key[i] = full threefry output at counter (0, i)
  uint32_t kp0, kp1, ku0, ku1;
  tf2x32(0u, 42u, 0u, 0u, kp0, kp1);
  tf2x32(0u, 42u, 0u, 1u, ku0, ku1);

  // Host-precompute the Poisson rng-split chain (row-independent):
  // per iter: subkey = tf(rng; 0,1); rng = tf(rng; 0,0)
  PoisKeys pk;
  {
    uint32_t r0 = kp0, r1 = kp1;
    for (int it = 0; it < 32; ++it) {
      uint32_t s0, s1, t0, t1;
      tf2x32(r0, r1, 0u, 1u, s0, s1);
      tf2x32(r0, r1, 0u, 0u, t0, t1);
      pk.s0[it] = s0; pk.s1[it] = s1;
      r0 = t0; r1 = t1;
    }
  }

  pois_kernel<<<(B + 255) / 256, 256, 0, stream>>>(nws, B, pk);
  rfm_kernel<<<(B + 3) / 4, 256, 0, stream>>>(x, mask, nws, out, B, ku0, ku1);
}